// Round 8
// baseline (111.397 us; speedup 1.0000x reference)
//
#include <hip/hip_runtime.h>
#include <hip/hip_bf16.h>

#define B_ROWS 4096
#define TWOB   8192
#define DIM    256
#define INV_T  14.285714285714286f  // 1/0.07

#define BM 128
#define BN 128
#define NQ 4              // col-chunk blocks per row tile: j = 8q..8q+7 (+ j=32 for q==3, rt<32)
// strip_sums sub-slots (one producer wave each -> plain stores, no atomics/zero-init):
//   0..63  : col-sum slot (jdist-1)*2 + wr, jdist = 1..32
//   64..71 : row-sum slot 64 + q*2 + wc
#define NSLOT 72

typedef __bf16 bf16x8 __attribute__((ext_vector_type(8)));
typedef float  f32x4  __attribute__((ext_vector_type(4)));

// ---------------- kernel 1: row L2-normalize, fp32 -> bf16 ----------------
// Also zeroes the finalize accumulators (ws is re-poisoned 0xAA before every launch).
__global__ __launch_bounds__(256) void normalize_k(const float* __restrict__ zi,
                                                   const float* __restrict__ zj,
                                                   unsigned short* __restrict__ zn,
                                                   float* __restrict__ loss_acc,
                                                   unsigned int* __restrict__ counter) {
    if (blockIdx.x == 0 && threadIdx.x == 0) {
        loss_acc[0] = 0.0f;
        counter[0]  = 0u;
    }
    int wave = threadIdx.x >> 6;
    int lane = threadIdx.x & 63;
    int row  = blockIdx.x * 4 + wave;             // 2048 blocks * 4 waves = 8192 rows
    const float* src = (row < B_ROWS) ? (zi + (size_t)row * DIM)
                                      : (zj + (size_t)(row - B_ROWS) * DIM);
    float4 v = reinterpret_cast<const float4*>(src)[lane];   // 64 lanes * 4 = 256
    float ss = v.x * v.x + v.y * v.y + v.z * v.z + v.w * v.w;
#pragma unroll
    for (int off = 32; off >= 1; off >>= 1) ss += __shfl_xor(ss, off);
    float norm = sqrtf(ss);
    norm = fmaxf(norm, 1e-8f);                    // COS_EPS
    float inv = 1.0f / norm;
    ushort4 o;
    o.x = __builtin_bit_cast(unsigned short, __float2bfloat16(v.x * inv));
    o.y = __builtin_bit_cast(unsigned short, __float2bfloat16(v.y * inv));
    o.z = __builtin_bit_cast(unsigned short, __float2bfloat16(v.z * inv));
    o.w = __builtin_bit_cast(unsigned short, __float2bfloat16(v.w * inv));
    reinterpret_cast<ushort4*>(zn)[(size_t)row * 64 + lane] = o;
}

// ---------------- kernel 2: symmetric flash NT-Xent main (pipelined) ----------------
// R7 math/tiling verbatim; kstep pipeline rebuilt per T3+T4:
//  - B ring-4 (32 KB): chunk C lives in slot C&3; stage C+3 issued at step C.
//  - counted s_waitcnt vmcnt(2) BEFORE the raw barrier: in-order vmcnt retirement
//    (m135) => all but the 2 newest loads retired => chunk T+1 resident for EVERY
//    wave at the barrier. Never drains to 0 mid-loop (tail ksteps of the last
//    tile use vmcnt(0): the stage stream has stopped so the count stops advancing).
//  - fragment REGISTER double-buffer: at step T, prefetch step T+1's 8 fragments
//    (A chunk (T+1)&7 from resident As, B slot (T+1)&3); lgkmcnt(8) waits only the
//    PREVIOUS prefetch; MFMA(T) runs on registers read a full kstep ago -> no
//    exposed ds_read latency, no drain. (R4 proved counted-vmcnt alone null; m133
//    proved reg-prefetch alone null; the combination removes both serial stalls.)
// LDS 64+32 = 96 KB -> 1 block/CU; grid 64x4 = 256 blocks = 1/CU single round.
__global__ __launch_bounds__(256, 1) void ntxent_main(const unsigned short* __restrict__ znu,
                                                      float* __restrict__ pos,
                                                      float* __restrict__ strip_sums) {
    const __bf16* zn = (const __bf16*)znu;
    __shared__ __attribute__((aligned(16))) __bf16 As[8][BM * 32];   // 8 kt-chunks x 8 KB = 64 KB
    __shared__ __attribute__((aligned(16))) __bf16 Bs[4][BN * 32];   // ring-4, 32 KB

    const int tid  = threadIdx.x;
    const int wave = tid >> 6;
    const int lane = tid & 63;
    const int wr = wave >> 1, wc = wave & 1;
    const int quad = lane >> 4, lc = lane & 15;
    const int rt = blockIdx.x;           // row-tile 0..63
    const int q  = blockIdx.y;           // col-chunk 0..3
    const int row0 = rt * BM;
    const int NCT = (q == 3 && rt < 32) ? 9 : 8;   // tile ct: jdist = 8q+ct (ct<8), 32 (ct==8)

    // staging: per-lane global element offsets (involution swizzle, proven R0-R7)
    int stg_off[2];
#pragma unroll
    for (int t = 0; t < 2; ++t) {
        int c  = (wave * 2 + t) * 64 + lane;
        int m  = c >> 2;
        int kc = (c & 3) ^ ((m & 3) ^ ((m >> 2) & 3));
        stg_off[t] = m * DIM + kc * 8;
    }

    // fragment-read byte offsets within one 8KB chunk (swizzle depends only on lc)
    const int sw    = (lc & 3) ^ ((lc >> 2) & 3);
    const int aBase = (wr * 64 + lc) * 64 + ((quad ^ sw) * 16);
    const int bBase = (wc * 64 + lc) * 64 + ((quad ^ sw) * 16);

// stage B chunk C (k-step index): tile C>>3, k-chunk C&7, ring slot C&3
#define STAGEC(C_) do { \
        const int tC_ = (C_) >> 3; \
        const int jd_ = (tC_ == 8) ? 32 : (q * 8 + tC_); \
        const int c0_ = ((rt + jd_) & 63) * BN; \
        _Pragma("unroll") \
        for (int t_ = 0; t_ < 2; ++t_) { \
            const int j_ = wave * 2 + t_; \
            const __bf16* gb_ = zn + c0_ * DIM + ((C_) & 7) * 32 + stg_off[t_]; \
            __builtin_amdgcn_global_load_lds( \
                (const __attribute__((address_space(1))) void*)gb_, \
                (__attribute__((address_space(3))) void*)((char*)Bs + ((C_) & 3) * 8192 + j_ * 1024), 16, 0, 0); \
        } } while (0)

    // ---- prologue: stage full A (8 chunks) then B chunks 0,1,2 ----
#pragma unroll
    for (int kt = 0; kt < 8; ++kt) {
#pragma unroll
        for (int t = 0; t < 2; ++t) {
            const int j = wave * 2 + t;
            const __bf16* ga = zn + row0 * DIM + kt * 32 + stg_off[t];
            __builtin_amdgcn_global_load_lds(
                (const __attribute__((address_space(1))) void*)ga,
                (__attribute__((address_space(3))) void*)((char*)As + kt * 8192 + j * 1024), 16, 0, 0);
        }
    }
    STAGEC(0); STAGEC(1); STAGEC(2);

    f32x4 acc[4][4];
    bf16x8 afr[2][4], bfr[2][4];
    float rsum[4][4];
    float posv[4] = {0.f, 0.f, 0.f, 0.f};
    int   posm[4] = {-1, -1, -1, -1};
#pragma unroll
    for (int mi = 0; mi < 4; ++mi)
#pragma unroll
        for (int r = 0; r < 4; ++r) rsum[mi][r] = 0.0f;

    // all-but-4 retired => A + chunk0 resident for every wave (newest 4 = chunks 1,2)
    asm volatile("s_waitcnt vmcnt(4)" ::: "memory");
    __builtin_amdgcn_s_barrier();
    __builtin_amdgcn_sched_barrier(0);
    // pre-read fragments for step 0 into parity 0
#pragma unroll
    for (int mi = 0; mi < 4; ++mi)
        afr[0][mi] = *(const bf16x8*)((const char*)As + aBase + mi * 1024);
#pragma unroll
    for (int ni = 0; ni < 4; ++ni)
        bfr[0][ni] = *(const bf16x8*)((const char*)Bs + bBase + ni * 1024);

// one k-step (KT compile-time): counted wait -> barrier -> stage T+3 -> prefetch
// frags T+1 (other reg parity) -> lgkmcnt(8) (waits PREVIOUS prefetch only) ->
// MFMA(T) on registers. Slot-reuse safety: chunk T-1 (slot of T+3) was prefetch-
// read at step T-2 and lgkm-waited before MFMA(T-1), which precedes barrier T.
#define KSTEP(KT) do { \
        if (ct == NCT - 1 && (KT) >= 5) { asm volatile("s_waitcnt vmcnt(0)" ::: "memory"); } \
        else                            { asm volatile("s_waitcnt vmcnt(2)" ::: "memory"); } \
        __builtin_amdgcn_s_barrier(); \
        __builtin_amdgcn_sched_barrier(0); \
        { const int C_ = ct * 8 + (KT) + 3; \
          if ((C_ >> 3) < NCT) STAGEC(C_); } \
        _Pragma("unroll") \
        for (int mi = 0; mi < 4; ++mi) \
            afr[((KT) + 1) & 1][mi] = *(const bf16x8*)((const char*)As + (((KT) + 1) & 7) * 8192 + aBase + mi * 1024); \
        _Pragma("unroll") \
        for (int ni = 0; ni < 4; ++ni) \
            bfr[((KT) + 1) & 1][ni] = *(const bf16x8*)((const char*)Bs + (((KT) + 1) & 3) * 8192 + bBase + ni * 1024); \
        asm volatile("s_waitcnt lgkmcnt(8)" ::: "memory"); \
        __builtin_amdgcn_sched_barrier(0); \
        __builtin_amdgcn_s_setprio(1); \
        _Pragma("unroll") \
        for (int mi = 0; mi < 4; ++mi) \
            _Pragma("unroll") \
            for (int ni = 0; ni < 4; ++ni) \
                acc[mi][ni] = __builtin_amdgcn_mfma_f32_16x16x32_bf16( \
                    afr[(KT) & 1][mi], bfr[(KT) & 1][ni], acc[mi][ni], 0, 0, 0); \
        __builtin_amdgcn_s_setprio(0); \
    } while (0)

#pragma unroll 1
    for (int ct = 0; ct < NCT; ++ct) {
        const int jdist = (ct == 8) ? 32 : (q * 8 + ct);
        const int col0  = ((rt + jdist) & 63) * BN;
#pragma unroll
        for (int mi = 0; mi < 4; ++mi)
#pragma unroll
            for (int ni = 0; ni < 4; ++ni) acc[mi][ni] = f32x4{0.f, 0.f, 0.f, 0.f};

        KSTEP(0); KSTEP(1); KSTEP(2); KSTEP(3);
        KSTEP(4); KSTEP(5); KSTEP(6); KSTEP(7);

        // epilogue: exp + row sums (C/D: row = quad*4+r, col = lc) + col sums.
        // Overlaps the next tile's in-flight stages (no barriers, no LDS).
        const bool isDiag = (jdist == 0);
        const bool isPos  = (jdist == 32);
        float cadd[4] = {0.f, 0.f, 0.f, 0.f};
#pragma unroll
        for (int mi = 0; mi < 4; ++mi) {
#pragma unroll
            for (int ni = 0; ni < 4; ++ni) {
                f32x4 a = acc[mi][ni];
#pragma unroll
                for (int r = 0; r < 4; ++r) {
                    float logit = a[r] * INV_T;
                    float e = __expf(logit);
                    if (isDiag || isPos) {
                        int gr = row0 + wr * 64 + mi * 16 + quad * 4 + r;
                        int gc = col0 + wc * 64 + ni * 16 + lc;
                        if (isPos && gc == gr + B_ROWS) { posv[mi] = logit; posm[mi] = gr; }
                        if (isDiag && gr == gc) e = 0.0f;    // diagonal mask
                    }
                    rsum[mi][r] += e;
                    cadd[ni]    += e;
                }
            }
        }

        // col-sum flush: quad reduce then direct store to the per-wave sub-slot
        // (unique producer -> no atomics, no barrier, no LDS). The 4 stores add
        // uniform vmcnt counts; in-order retirement keeps the counted waits safe.
        if (!isDiag) {
#pragma unroll
            for (int ni = 0; ni < 4; ++ni) {
                cadd[ni] += __shfl_xor(cadd[ni], 16);   // sum over quad bit 0
                cadd[ni] += __shfl_xor(cadd[ni], 32);   // sum over quad bit 1
            }
            if (quad == 0) {
                float* dst = strip_sums + (size_t)((jdist - 1) * 2 + wr) * TWOB + col0 + wc * 64 + lc;
#pragma unroll
                for (int ni = 0; ni < 4; ++ni) dst[ni * 16] = cadd[ni];
            }
        }
    }

    // deferred pos stores: j==32 tiles hold both directions of each positive pair
#pragma unroll
    for (int mi = 0; mi < 4; ++mi)
        if (posm[mi] >= 0) {
            pos[posm[mi]] = posv[mi];
            pos[posm[mi] + B_ROWS] = posv[mi];
        }

    // row-sum flush: lane reduce over lc bits then direct store to per-wave sub-slot
    {
        float* rdst = strip_sums + (size_t)(64 + q * 2 + wc) * TWOB + row0 + wr * 64;
#pragma unroll
        for (int mi = 0; mi < 4; ++mi) {
#pragma unroll
            for (int r = 0; r < 4; ++r) {
                float v = rsum[mi][r];
                v += __shfl_xor(v, 1);
                v += __shfl_xor(v, 2);
                v += __shfl_xor(v, 4);
                v += __shfl_xor(v, 8);
                if (lc == 0) rdst[mi * 16 + quad * 4 + r] = v;
            }
        }
    }
}

// ---------------- kernel 3: loss = mean(log(sumexp) - pos) ----------------
// Row r coverage: col sub-slots 0..61 (j=1..31) for all rows; 62,63 (j=32) only
// for rows >= 4096 (rows < 4096 get distance-32 via the row-sum path); row
// sub-slots 64..71. Exactly the 64 tile-distances once each.
__global__ __launch_bounds__(256) void finalize_k(const float* __restrict__ strip_sums,
                                                  const float* __restrict__ pos,
                                                  float* __restrict__ loss_acc,
                                                  unsigned int* __restrict__ counter,
                                                  float* __restrict__ out) {
    __shared__ float wsums[4];
    const int tid = threadIdx.x;
    const int r   = blockIdx.x * 256 + tid;
    float s = 0.0f;
#pragma unroll
    for (int t = 0; t < 62; ++t) s += strip_sums[(size_t)t * TWOB + r];
    if (r >= B_ROWS) {
        s += strip_sums[(size_t)62 * TWOB + r];
        s += strip_sums[(size_t)63 * TWOB + r];
    }
#pragma unroll
    for (int t = 64; t < 72; ++t) s += strip_sums[(size_t)t * TWOB + r];
    float local = logf(s) - pos[r];
#pragma unroll
    for (int off = 32; off >= 1; off >>= 1) local += __shfl_xor(local, off);
    if ((tid & 63) == 0) wsums[tid >> 6] = local;
    __syncthreads();
    if (tid == 0) {
        float bsum = wsums[0] + wsums[1] + wsums[2] + wsums[3];
        atomicAdd(loss_acc, bsum);
        __threadfence();                              // order loss add before counter add
        unsigned int done = atomicAdd(counter, 1u);
        if (done == gridDim.x - 1) {
            float total = atomicAdd(loss_acc, 0.0f);  // device-scope atomic read
            out[0] = total / (float)TWOB;
        }
    }
}

extern "C" void kernel_launch(void* const* d_in, const int* in_sizes, int n_in,
                              void* d_out, int out_size, void* d_ws, size_t ws_size,
                              hipStream_t stream) {
    const float* zi = (const float*)d_in[0];
    const float* zj = (const float*)d_in[1];
    // ws layout: zn (4 MB) | pos (32 KB) | strip_sums (72 slots x 32 KB = 2.25 MB) | loss_acc | counter
    unsigned short* zn = (unsigned short*)d_ws;
    float* pos        = (float*)((char*)d_ws + (size_t)TWOB * DIM * 2);
    float* strip_sums = pos + TWOB;
    float* loss_acc   = strip_sums + (size_t)NSLOT * TWOB;
    unsigned int* counter = (unsigned int*)(loss_acc + 1);
    float* out = (float*)d_out;

    normalize_k<<<dim3(TWOB / 4), 256, 0, stream>>>(zi, zj, zn, loss_acc, counter);
    ntxent_main<<<dim3(64, NQ), 256, 0, stream>>>(zn, pos, strip_sums);
    finalize_k<<<dim3(TWOB / 256), 256, 0, stream>>>(strip_sums, pos, loss_acc, counter, out);
}

// Round 9
// 97.742 us; speedup vs baseline: 1.1397x; 1.1397x over previous
//
#include <hip/hip_runtime.h>
#include <hip/hip_bf16.h>

#define B_ROWS 4096
#define TWOB   8192
#define DIM    256
#define INV_T  14.285714285714286f  // 1/0.07

#define BM 128
#define BN 128
#define NQ 8              // col-chunk blocks per row tile (4 tiles each, q==7&&rt<32 has 5)
// strip_sums sub-slots (one producer wave each -> plain stores, no atomics/zero-init):
//   0..63  : col-sum slot (jdist-1)*2 + wr, jdist = 1..32
//   64..79 : row-sum slot 64 + q*2 + wc
#define NSLOT 80

typedef __bf16 bf16x8 __attribute__((ext_vector_type(8)));
typedef float  f32x4  __attribute__((ext_vector_type(4)));

// ---------------- kernel 1: row L2-normalize, fp32 -> bf16 ----------------
// Also zeroes the finalize accumulators (ws is re-poisoned 0xAA before every launch).
__global__ __launch_bounds__(256) void normalize_k(const float* __restrict__ zi,
                                                   const float* __restrict__ zj,
                                                   unsigned short* __restrict__ zn,
                                                   float* __restrict__ loss_acc,
                                                   unsigned int* __restrict__ counter) {
    if (blockIdx.x == 0 && threadIdx.x == 0) {
        loss_acc[0] = 0.0f;
        counter[0]  = 0u;
    }
    int wave = threadIdx.x >> 6;
    int lane = threadIdx.x & 63;
    int row  = blockIdx.x * 4 + wave;             // 2048 blocks * 4 waves = 8192 rows
    const float* src = (row < B_ROWS) ? (zi + (size_t)row * DIM)
                                      : (zj + (size_t)(row - B_ROWS) * DIM);
    float4 v = reinterpret_cast<const float4*>(src)[lane];   // 64 lanes * 4 = 256
    float ss = v.x * v.x + v.y * v.y + v.z * v.z + v.w * v.w;
#pragma unroll
    for (int off = 32; off >= 1; off >>= 1) ss += __shfl_xor(ss, off);
    float norm = sqrtf(ss);
    norm = fmaxf(norm, 1e-8f);                    // COS_EPS
    float inv = 1.0f / norm;
    ushort4 o;
    o.x = __builtin_bit_cast(unsigned short, __float2bfloat16(v.x * inv));
    o.y = __builtin_bit_cast(unsigned short, __float2bfloat16(v.y * inv));
    o.z = __builtin_bit_cast(unsigned short, __float2bfloat16(v.z * inv));
    o.w = __builtin_bit_cast(unsigned short, __float2bfloat16(v.w * inv));
    reinterpret_cast<ushort4*>(zn)[(size_t)row * 64 + lane] = o;
}

// ---------------- kernel 2: symmetric flash NT-Xent main ----------------
// sim = zn@zn^T is SYMMETRIC: each off-diagonal tile (r,c) supplies row sums for
// rows of r (rsum regs) AND, via its col sums, row sums for rows of c. Upper band
// only: block (rt,q) handles col tiles c=(rt+j)&63, j in {4q..4q+3} (+ j=32 for
// q==7, rt<32) -> 2080 of 4096 tiles. Compute loop = R0's verified structure
// (A LDS-resident staged once, B ping-pong staged one kstep ahead, 80 KB LDS).
// R9 change vs R7: __launch_bounds__(256, 2) — forces <=128 VGPR so the 80 KB
// LDS kernel actually gets 2 blocks/CU. R0 compiled to 100 VGPR by luck; R6/R7
// (unbounded) could exceed 128 -> 1 block/CU, explaining their ~1.7x per-tile
// cost vs R0 (R8 independently measured 4-waves/CU of this family at 58 us).
__global__ __launch_bounds__(256, 2) void ntxent_main(const unsigned short* __restrict__ znu,
                                                      float* __restrict__ pos,
                                                      float* __restrict__ strip_sums) {
    const __bf16* zn = (const __bf16*)znu;
    __shared__ __attribute__((aligned(16))) __bf16 As[8][BM * 32];   // 8 kt-chunks x 8 KB = 64 KB
    __shared__ __attribute__((aligned(16))) __bf16 Bs[2][BN * 32];   // ping-pong, 16 KB

    const int tid  = threadIdx.x;
    const int wave = tid >> 6;
    const int lane = tid & 63;
    const int wr = wave >> 1, wc = wave & 1;
    const int quad = lane >> 4, lc = lane & 15;
    const int rt = blockIdx.x;           // row-tile 0..63
    const int q  = blockIdx.y;           // col-chunk 0..7
    const int q4 = q * 4;
    const int row0 = rt * BM;
    const int NCT = (q == 7 && rt < 32) ? 5 : 4;
#define COLOF(i) ((rt + (((i) == 4) ? 32 : (q4 + (i)))) & 63)

    // staging: per-lane global element offsets for this wave's two 1KB chunks per stage.
    // chunk c = j*64+lane -> (m=c>>2, kc_lds=c&3); source kc_g = kc_lds ^ sw(m)  (involution)
    int stg_off[2];
#pragma unroll
    for (int t = 0; t < 2; ++t) {
        int c  = (wave * 2 + t) * 64 + lane;
        int m  = c >> 2;
        int kc = (c & 3) ^ ((m & 3) ^ ((m >> 2) & 3));
        stg_off[t] = m * DIM + kc * 8;
    }

    // fragment-read byte offsets within one 8KB chunk (swizzle depends only on m&15 == lc)
    const int sw    = (lc & 3) ^ ((lc >> 2) & 3);
    const int aBase = (wr * 64 + lc) * 64 + ((quad ^ sw) * 16);
    const int bBase = (wc * 64 + lc) * 64 + ((quad ^ sw) * 16);

    // ---- prologue: stage full A (8 chunks) + first B chunk ----
#pragma unroll
    for (int kt = 0; kt < 8; ++kt) {
#pragma unroll
        for (int t = 0; t < 2; ++t) {
            const int j = wave * 2 + t;
            const __bf16* ga = zn + row0 * DIM + kt * 32 + stg_off[t];
            __builtin_amdgcn_global_load_lds(
                (const __attribute__((address_space(1))) void*)ga,
                (__attribute__((address_space(3))) void*)((char*)As + kt * 8192 + j * 1024), 16, 0, 0);
        }
    }
    {
        const int col0 = COLOF(0) * BN;
#pragma unroll
        for (int t = 0; t < 2; ++t) {
            const int j = wave * 2 + t;
            const __bf16* gb = zn + col0 * DIM + stg_off[t];
            __builtin_amdgcn_global_load_lds(
                (const __attribute__((address_space(1))) void*)gb,
                (__attribute__((address_space(3))) void*)((char*)Bs + j * 1024), 16, 0, 0);
        }
    }

    f32x4 acc[4][4];
    float rsum[4][4];
    float posv[4] = {0.f, 0.f, 0.f, 0.f};
    int   posm[4] = {-1, -1, -1, -1};
#pragma unroll
    for (int mi = 0; mi < 4; ++mi)
#pragma unroll
        for (int r = 0; r < 4; ++r) rsum[mi][r] = 0.0f;

    for (int ct = 0; ct < NCT; ++ct) {
        const int jdist = (ct == 4) ? 32 : (q4 + ct);
        const int c     = (rt + jdist) & 63;
        const int col0  = c * BN;
#pragma unroll
        for (int mi = 0; mi < 4; ++mi)
#pragma unroll
            for (int ni = 0; ni < 4; ++ni) acc[mi][ni] = f32x4{0.f, 0.f, 0.f, 0.f};

#pragma unroll
        for (int kt = 0; kt < 8; ++kt) {
            // barrier: (a) drains the B stage issued one iteration ago (covered
            // by that iteration's compute), (b) guards reuse of Bs[kt+1 & 1].
            __syncthreads();

            // stage next B chunk into the other buffer
            {
                const int nct = (kt == 7) ? ct + 1 : ct;
                const int nkt = (kt + 1) & 7;
                if (nct < NCT) {
                    const int ncol0 = COLOF(nct) * BN;
#pragma unroll
                    for (int t = 0; t < 2; ++t) {
                        const int j = wave * 2 + t;
                        const __bf16* gb = zn + ncol0 * DIM + nkt * 32 + stg_off[t];
                        __builtin_amdgcn_global_load_lds(
                            (const __attribute__((address_space(1))) void*)gb,
                            (__attribute__((address_space(3))) void*)((char*)Bs + ((kt + 1) & 1) * 8192 + j * 1024),
                            16, 0, 0);
                    }
                }
            }

            bf16x8 af[4], bfr[4];
#pragma unroll
            for (int mi = 0; mi < 4; ++mi)
                af[mi] = *(const bf16x8*)((const char*)As + kt * 8192 + aBase + mi * 1024);
#pragma unroll
            for (int ni = 0; ni < 4; ++ni)
                bfr[ni] = *(const bf16x8*)((const char*)Bs + (kt & 1) * 8192 + bBase + ni * 1024);
#pragma unroll
            for (int mi = 0; mi < 4; ++mi)
#pragma unroll
                for (int ni = 0; ni < 4; ++ni)
                    acc[mi][ni] = __builtin_amdgcn_mfma_f32_16x16x32_bf16(
                        af[mi], bfr[ni], acc[mi][ni], 0, 0, 0);
        }

        // epilogue: exp + row sums (C/D layout: row = quad*4+reg, col = lc) + col sums.
        // Runs while the next tile's kt=0 B stage is in flight (no barriers here).
        const bool isDiag = (jdist == 0);
        const bool isPos  = (jdist == 32);
        float cadd[4] = {0.f, 0.f, 0.f, 0.f};
#pragma unroll
        for (int mi = 0; mi < 4; ++mi) {
#pragma unroll
            for (int ni = 0; ni < 4; ++ni) {
                f32x4 a = acc[mi][ni];
#pragma unroll
                for (int r = 0; r < 4; ++r) {
                    float logit = a[r] * INV_T;
                    float e = __expf(logit);
                    if (isDiag || isPos) {
                        int gr = row0 + wr * 64 + mi * 16 + quad * 4 + r;
                        int gc = col0 + wc * 64 + ni * 16 + lc;
                        if (isPos && gc == gr + B_ROWS) { posv[mi] = logit; posm[mi] = gr; }
                        if (isDiag && gr == gc) e = 0.0f;    // diagonal mask
                    }
                    rsum[mi][r] += e;
                    cadd[ni]    += e;
                }
            }
        }

        // col-sum flush: quad reduce (rows within wave) then DIRECT store to the
        // per-wave sub-slot (unique producer -> no atomics, no barrier, no LDS).
        if (!isDiag) {
#pragma unroll
            for (int ni = 0; ni < 4; ++ni) {
                cadd[ni] += __shfl_xor(cadd[ni], 16);   // sum over quad bit 0
                cadd[ni] += __shfl_xor(cadd[ni], 32);   // sum over quad bit 1
            }
            if (quad == 0) {
                float* dst = strip_sums + (size_t)((jdist - 1) * 2 + wr) * TWOB + col0 + wc * 64 + lc;
#pragma unroll
                for (int ni = 0; ni < 4; ++ni) dst[ni * 16] = cadd[ni];
            }
        }
    }

    // deferred pos stores: j==32 tiles hold both directions of each positive pair
#pragma unroll
    for (int mi = 0; mi < 4; ++mi)
        if (posm[mi] >= 0) {
            pos[posm[mi]] = posv[mi];
            pos[posm[mi] + B_ROWS] = posv[mi];
        }

    // row-sum flush: lane reduce over lc bits then DIRECT store to per-wave sub-slot.
    {
        float* rdst = strip_sums + (size_t)(64 + q * 2 + wc) * TWOB + row0 + wr * 64;
#pragma unroll
        for (int mi = 0; mi < 4; ++mi) {
#pragma unroll
            for (int r = 0; r < 4; ++r) {
                float v = rsum[mi][r];
                v += __shfl_xor(v, 1);
                v += __shfl_xor(v, 2);
                v += __shfl_xor(v, 4);
                v += __shfl_xor(v, 8);
                if (lc == 0) rdst[mi * 16 + quad * 4 + r] = v;
            }
        }
    }
}

// ---------------- kernel 3: loss = mean(log(sumexp) - pos) ----------------
// Row r coverage: col sub-slots 0..61 (j=1..31, both wr) for all rows; 62,63
// (j=32) only for rows >= 4096 (rows < 4096 get distance-32 via row-sum path);
// row sub-slots 64..79. Exactly the 64 tile-distances once each.
__global__ __launch_bounds__(256) void finalize_k(const float* __restrict__ strip_sums,
                                                  const float* __restrict__ pos,
                                                  float* __restrict__ loss_acc,
                                                  unsigned int* __restrict__ counter,
                                                  float* __restrict__ out) {
    __shared__ float wsums[4];
    const int tid = threadIdx.x;
    const int r   = blockIdx.x * 256 + tid;
    float s = 0.0f;
#pragma unroll
    for (int t = 0; t < 62; ++t) s += strip_sums[(size_t)t * TWOB + r];
    if (r >= B_ROWS) {
        s += strip_sums[(size_t)62 * TWOB + r];
        s += strip_sums[(size_t)63 * TWOB + r];
    }
#pragma unroll
    for (int t = 64; t < 80; ++t) s += strip_sums[(size_t)t * TWOB + r];
    float local = logf(s) - pos[r];
#pragma unroll
    for (int off = 32; off >= 1; off >>= 1) local += __shfl_xor(local, off);
    if ((tid & 63) == 0) wsums[tid >> 6] = local;
    __syncthreads();
    if (tid == 0) {
        float bsum = wsums[0] + wsums[1] + wsums[2] + wsums[3];
        atomicAdd(loss_acc, bsum);
        __threadfence();                              // order loss add before counter add
        unsigned int done = atomicAdd(counter, 1u);
        if (done == gridDim.x - 1) {
            float total = atomicAdd(loss_acc, 0.0f);  // device-scope atomic read
            out[0] = total / (float)TWOB;
        }
    }
}

extern "C" void kernel_launch(void* const* d_in, const int* in_sizes, int n_in,
                              void* d_out, int out_size, void* d_ws, size_t ws_size,
                              hipStream_t stream) {
    const float* zi = (const float*)d_in[0];
    const float* zj = (const float*)d_in[1];
    // ws layout: zn (4 MB) | pos (32 KB) | strip_sums (80 slots x 32 KB = 2.56 MB) | loss_acc | counter
    unsigned short* zn = (unsigned short*)d_ws;
    float* pos        = (float*)((char*)d_ws + (size_t)TWOB * DIM * 2);
    float* strip_sums = pos + TWOB;
    float* loss_acc   = strip_sums + (size_t)NSLOT * TWOB;
    unsigned int* counter = (unsigned int*)(loss_acc + 1);
    float* out = (float*)d_out;

    normalize_k<<<dim3(TWOB / 4), 256, 0, stream>>>(zi, zj, zn, loss_acc, counter);
    ntxent_main<<<dim3(64, NQ), 256, 0, stream>>>(zn, pos, strip_sums);
    finalize_k<<<dim3(TWOB / 256), 256, 0, stream>>>(strip_sums, pos, loss_acc, counter, out);
}